// Round 2
// baseline (709.834 us; speedup 1.0000x reference)
//
#include <hip/hip_runtime.h>
#include <stdint.h>

typedef unsigned int u32;
typedef unsigned short u16;

#define NROWS 100000
#define DIM 512
#define HDIM 1024
#define OUTF 250
#define NSEG 256
#define LNEPS 1e-5f
#define NG 1563            // ceil(NROWS/64)
#define GATE_BLOCKS 256

typedef __bf16 bf16_t;
typedef bf16_t bf16x8 __attribute__((ext_vector_type(8)));
typedef float f32x4 __attribute__((ext_vector_type(4)));

__device__ inline u16 f2bf(float f) {
    u32 u = __float_as_uint(f);
    u = (u + 0x7FFFu + ((u >> 16) & 1u)) >> 16;
    return (u16)u;
}
__device__ inline u32 pack2(float a, float b) {
    return (u32)f2bf(a) | ((u32)f2bf(b) << 16);
}

__device__ inline int lower_bound(const int* __restrict__ a, int n, int v) {
    int lo = 0, hi = n;
    while (lo < hi) {
        int m = (lo + hi) >> 1;
        if (a[m] < v) lo = m + 1; else hi = m;
    }
    return lo;
}

// ---------------------------------------------------------------------------
// Kernel 0: convert gW1 [1024][512] fp32 -> bf16 fragments in MFMA-linear order
// Wf layout: [ks(16)][nt(64)][lane(64)] x 16B ; element (lane,j):
//   n = nt*16 + (lane&15), k = ks*32 + (lane>>4)*8 + j
// ---------------------------------------------------------------------------
__global__ __launch_bounds__(256) void k_wconv(const float* __restrict__ gW1,
                                               u16* __restrict__ Wf) {
    int gid  = blockIdx.x * 256 + threadIdx.x;   // 0..65535
    int lane = gid & 63;
    int grp  = gid >> 6;                         // ks*64 + nt
    int ks   = grp >> 6, nt = grp & 63;
    int n    = nt * 16 + (lane & 15);
    int k0   = ks * 32 + ((lane >> 4) << 3);
    const float* src = gW1 + (size_t)n * DIM + k0;
    float4 f0 = *reinterpret_cast<const float4*>(src);
    float4 f1 = *reinterpret_cast<const float4*>(src + 4);
    uint4 val;
    val.x = pack2(f0.x, f0.y); val.y = pack2(f0.z, f0.w);
    val.z = pack2(f1.x, f1.y); val.w = pack2(f1.z, f1.w);
    reinterpret_cast<uint4*>(Wf)[gid] = val;
}

// ---------------------------------------------------------------------------
// Kernel 1: fused  gate[i] = relu(LN(x_i @ gW1.T + gb1)) . gW2 + gb2
// Persistent: grid=256 blocks (1/CU), 512 threads (8 waves).
// Each block loops over 64-row groups g = blk, blk+256, ... with LDS
// double-buffer; staging of group g+256 is interleaved into group g's
// barrier-free K-loop. Wave tile: M=64 (4 m-tiles) x N=128 (8 n-tiles).
// ---------------------------------------------------------------------------
__global__ __launch_bounds__(512) void k_gate(
    const float* __restrict__ x, const u16* __restrict__ Wf,
    const float* __restrict__ gb1,
    const float* __restrict__ gln_g, const float* __restrict__ gln_b,
    const float* __restrict__ gW2, const float* __restrict__ gb2,
    float* __restrict__ gate)
{
    __shared__ __align__(16) u16 xlds[2][64 * DIM];   // 2 x 64KB
    __shared__ float redS[8][64];
    __shared__ float redQ[8][64];
    __shared__ float meanA[64], rstdA[64];

    const int tid  = threadIdx.x;
    const int lane = tid & 63;
    const int w    = tid >> 6;          // wave 0..7
    const int l15  = lane & 15;
    const int g4   = lane >> 4;         // 0..3

    const bf16x8* __restrict__ WfB = reinterpret_cast<const bf16x8*>(Wf);

    // one staging unit = 8 bf16 elements (32B fp32 read, 16B LDS write)
    auto stage_unit = [&](int g, int buf, int lu) {
        int r = lu >> 6;                 // local row 0..63
        int u = lu & 63;                 // unit in row
        int row = g * 64 + r;
        row = (row < NROWS) ? row : (NROWS - 1);
        const float* src = x + (size_t)row * DIM + (u << 3);
        float4 f0 = *reinterpret_cast<const float4*>(src);
        float4 f1 = *reinterpret_cast<const float4*>(src + 4);
        bf16x8 v;
        v[0] = (bf16_t)f0.x; v[1] = (bf16_t)f0.y;
        v[2] = (bf16_t)f0.z; v[3] = (bf16_t)f0.w;
        v[4] = (bf16_t)f1.x; v[5] = (bf16_t)f1.y;
        v[6] = (bf16_t)f1.z; v[7] = (bf16_t)f1.w;
        int phys = r * DIM + ((u ^ (r & 7)) << 3);   // swizzled, u16 units
        *reinterpret_cast<bf16x8*>(&xlds[buf][phys]) = v;
    };

    const int g0 = blockIdx.x;
    #pragma unroll
    for (int uu = 0; uu < 8; ++uu) stage_unit(g0, 0, uu * 512 + tid);

    int cur = 0;
    for (int g = g0; g < NG; g += GATE_BLOCKS) {
        __syncthreads();                 // buf[cur] staged; redS free
        const int gn = g + GATE_BLOCKS;
        const bool doNext = (gn < NG);

        f32x4 acc[4][8];
        #pragma unroll
        for (int m = 0; m < 4; ++m)
            #pragma unroll
            for (int t = 0; t < 8; ++t)
                acc[m][t] = (f32x4){0.f, 0.f, 0.f, 0.f};

        const u16* xl = xlds[cur];

        #pragma unroll
        for (int ks = 0; ks < 16; ++ks) {
            if (ks < 8) {
                if (doNext) stage_unit(gn, cur ^ 1, ks * 512 + tid);
            }
            bf16x8 b[8];
            #pragma unroll
            for (int t = 0; t < 8; ++t)
                b[t] = WfB[(ks * 64 + w * 8 + t) * 64 + lane];
            bf16x8 a[4];
            #pragma unroll
            for (int m = 0; m < 4; ++m) {
                int r = m * 16 + l15;
                int u = ks * 4 + g4;
                int phys = r * DIM + ((u ^ (r & 7)) << 3);
                a[m] = *reinterpret_cast<const bf16x8*>(&xl[phys]);
            }
            #pragma unroll
            for (int m = 0; m < 4; ++m)
                #pragma unroll
                for (int t = 0; t < 8; ++t)
                    acc[m][t] = __builtin_amdgcn_mfma_f32_16x16x32_bf16(a[m], b[t], acc[m][t], 0, 0, 0);
        }

        // ---- bias add (affects LN stats)
        float cbias[8];
        #pragma unroll
        for (int t = 0; t < 8; ++t) cbias[t] = gb1[(w * 8 + t) * 16 + l15];
        #pragma unroll
        for (int m = 0; m < 4; ++m)
            #pragma unroll
            for (int t = 0; t < 8; ++t)
                #pragma unroll
                for (int j = 0; j < 4; ++j)
                    acc[m][t][j] += cbias[t];

        // ---- per-row LN stats, streamed per row-slot (low reg pressure)
        #pragma unroll
        for (int m = 0; m < 4; ++m) {
            #pragma unroll
            for (int j = 0; j < 4; ++j) {
                float s1 = 0.f, s2 = 0.f;
                #pragma unroll
                for (int t = 0; t < 8; ++t) {
                    float v = acc[m][t][j];
                    s1 += v; s2 += v * v;
                }
                #pragma unroll
                for (int off = 1; off < 16; off <<= 1) {
                    s1 += __shfl_xor(s1, off);
                    s2 += __shfl_xor(s2, off);
                }
                if (l15 == 0) {
                    int row = m * 16 + g4 * 4 + j;
                    redS[w][row] = s1;
                    redQ[w][row] = s2;
                }
            }
        }
        __syncthreads();
        if (tid < 64) {
            float S1 = 0.f, S2 = 0.f;
            #pragma unroll
            for (int ww = 0; ww < 8; ++ww) { S1 += redS[ww][tid]; S2 += redQ[ww][tid]; }
            float mean = S1 * (1.0f / 1024.0f);
            float var  = S2 * (1.0f / 1024.0f) - mean * mean;
            meanA[tid] = mean;
            rstdA[tid] = rsqrtf(var + LNEPS);
        }
        __syncthreads();

        // ---- LN + relu + dot(gW2), streamed per row-slot
        float cg[8], cb[8], cw[8];
        #pragma unroll
        for (int t = 0; t < 8; ++t) {
            int c = (w * 8 + t) * 16 + l15;
            cg[t] = gln_g[c]; cb[t] = gln_b[c]; cw[t] = gW2[c];
        }
        #pragma unroll
        for (int m = 0; m < 4; ++m) {
            #pragma unroll
            for (int j = 0; j < 4; ++j) {
                int row = m * 16 + g4 * 4 + j;
                float mn = meanA[row];
                float rs = rstdA[row];
                float gp = 0.f;
                #pragma unroll
                for (int t = 0; t < 8; ++t) {
                    float h = (acc[m][t][j] - mn) * rs * cg[t] + cb[t];
                    gp += fmaxf(h, 0.f) * cw[t];
                }
                #pragma unroll
                for (int off = 1; off < 16; off <<= 1)
                    gp += __shfl_xor(gp, off);
                if (l15 == 0) redS[w][row] = gp;
            }
        }
        __syncthreads();
        if (tid < 64) {
            float s = gb2[0];
            #pragma unroll
            for (int ww = 0; ww < 8; ++ww) s += redS[ww][tid];
            int row = g * 64 + tid;
            if (row < NROWS) gate[row] = s;
        }
        cur ^= 1;
        // next iteration's top __syncthreads orders redS reuse + buffer swap
    }
}

// ---------------------------------------------------------------------------
// Kernel 2: fused segment softmax + weighted pooling.
// One block per segment (256 blocks, 128 threads). Gate values cached in LDS.
// ---------------------------------------------------------------------------
#define SEG_CACHE 2048
__global__ __launch_bounds__(128) void k_pool(const int* __restrict__ ids,
                                              const float* __restrict__ gate,
                                              const float* __restrict__ x,
                                              float* __restrict__ pooled) {
    const int b = blockIdx.x, tid = threadIdx.x;
    const int start = lower_bound(ids, NROWS, b);
    const int end   = lower_bound(ids, NROWS, b + 1);
    const int len   = end - start;
    __shared__ float eg[SEG_CACHE];
    __shared__ float red[2];

    // pass 1: max (and cache gate)
    float lm = -INFINITY;
    for (int i = tid; i < len; i += 128) {
        float v = gate[start + i];
        if (i < SEG_CACHE) eg[i] = v;
        lm = fmaxf(lm, v);
    }
    #pragma unroll
    for (int off = 32; off; off >>= 1) lm = fmaxf(lm, __shfl_xor(lm, off));
    if ((tid & 63) == 0) red[tid >> 6] = lm;
    __syncthreads();
    const float m = fmaxf(red[0], red[1]);
    __syncthreads();

    // pass 2: sum of exp (cache exp values)
    float ls = 0.f;
    for (int i = tid; i < len; i += 128) {
        float v = (i < SEG_CACHE) ? eg[i] : gate[start + i];
        float e = __expf(v - m);
        if (i < SEG_CACHE) eg[i] = e;
        ls += e;
    }
    #pragma unroll
    for (int off = 32; off; off >>= 1) ls += __shfl_xor(ls, off);
    if ((tid & 63) == 0) red[tid >> 6] = ls;
    __syncthreads();
    const float den = red[0] + red[1];
    const float inv = (den > 0.f) ? 1.0f / den : 0.0f;
    __syncthreads();   // eg[] writes visible to all before pass 3

    // pass 3: pooled[b][4t..4t+4) = sum_i w_i * x[i][4t..)
    float4 acc = {0.f, 0.f, 0.f, 0.f};
    const float4* xr = reinterpret_cast<const float4*>(x);
    #pragma unroll 4
    for (int i = 0; i < len; ++i) {
        float wgt = ((i < SEG_CACHE) ? eg[i] : __expf(gate[start + i] - m)) * inv;
        float4 xv = xr[(size_t)(start + i) * 128 + tid];
        acc.x += wgt * xv.x; acc.y += wgt * xv.y;
        acc.z += wgt * xv.z; acc.w += wgt * xv.w;
    }
    reinterpret_cast<float4*>(pooled)[b * 128 + tid] = acc;
}

// ---------------------------------------------------------------------------
// Kernel 3: fused head: out=LN(pooled); z=relu(LN(out@mW1.T+mb1)); logits=z@mW2.T+mb2
// ---------------------------------------------------------------------------
__device__ inline float block_sum(float v, float* sh, int tid) {
    #pragma unroll
    for (int off = 32; off; off >>= 1) v += __shfl_xor(v, off);
    if ((tid & 63) == 0) sh[tid >> 6] = v;
    __syncthreads();
    float r = sh[0] + sh[1] + sh[2] + sh[3];
    __syncthreads();
    return r;
}

__global__ __launch_bounds__(256) void k_head(
    const float* __restrict__ pooled,
    const float* __restrict__ pn_g, const float* __restrict__ pn_b,
    const float* __restrict__ mW1, const float* __restrict__ mb1,
    const float* __restrict__ mln_g, const float* __restrict__ mln_b,
    const float* __restrict__ mW2, const float* __restrict__ mb2,
    float* __restrict__ logits)
{
    const int b = blockIdx.x, tid = threadIdx.x;
    __shared__ float outr[DIM];
    __shared__ float zr[HDIM];
    __shared__ float shred[4];

    float v0 = pooled[b * DIM + tid];
    float v1 = pooled[b * DIM + 256 + tid];
    float S = block_sum(v0 + v1, shred, tid);
    float Q = block_sum(v0 * v0 + v1 * v1, shred, tid);
    float mean = S * (1.0f / 512.0f);
    float rstd = rsqrtf(Q * (1.0f / 512.0f) - mean * mean + LNEPS);
    outr[tid]       = (v0 - mean) * rstd * pn_g[tid] + pn_b[tid];
    outr[tid + 256] = (v1 - mean) * rstd * pn_g[tid + 256] + pn_b[tid + 256];
    __syncthreads();

    float y[4];
    #pragma unroll
    for (int q = 0; q < 4; ++q) {
        int f = q * 256 + tid;
        const float4* wr = reinterpret_cast<const float4*>(mW1 + (size_t)f * DIM);
        float acc = 0.f;
        #pragma unroll 8
        for (int kk = 0; kk < 128; ++kk) {
            float4 wv = wr[kk];
            acc += wv.x * outr[kk * 4 + 0] + wv.y * outr[kk * 4 + 1]
                 + wv.z * outr[kk * 4 + 2] + wv.w * outr[kk * 4 + 3];
        }
        y[q] = acc + mb1[f];
    }
    float S2 = block_sum(y[0] + y[1] + y[2] + y[3], shred, tid);
    float Q2 = block_sum(y[0]*y[0] + y[1]*y[1] + y[2]*y[2] + y[3]*y[3], shred, tid);
    float mean2 = S2 * (1.0f / 1024.0f);
    float rstd2 = rsqrtf(Q2 * (1.0f / 1024.0f) - mean2 * mean2 + LNEPS);
    #pragma unroll
    for (int q = 0; q < 4; ++q) {
        int f = q * 256 + tid;
        zr[f] = fmaxf((y[q] - mean2) * rstd2 * mln_g[f] + mln_b[f], 0.f);
    }
    __syncthreads();
    if (tid < OUTF) {
        const float4* wr = reinterpret_cast<const float4*>(mW2 + (size_t)tid * HDIM);
        float acc = 0.f;
        #pragma unroll 8
        for (int kk = 0; kk < 256; ++kk) {
            float4 wv = wr[kk];
            acc += wv.x * zr[kk * 4 + 0] + wv.y * zr[kk * 4 + 1]
                 + wv.z * zr[kk * 4 + 2] + wv.w * zr[kk * 4 + 3];
        }
        logits[b * OUTF + tid] = acc + mb2[tid];
    }
}

// ---------------------------------------------------------------------------
extern "C" void kernel_launch(void* const* d_in, const int* in_sizes, int n_in,
                              void* d_out, int out_size, void* d_ws, size_t ws_size,
                              hipStream_t stream) {
    const float* x     = (const float*)d_in[0];
    const int*   ids   = (const int*)  d_in[1];
    const float* gW1   = (const float*)d_in[2];
    const float* gb1   = (const float*)d_in[3];
    const float* gln_g = (const float*)d_in[4];
    const float* gln_b = (const float*)d_in[5];
    const float* gW2   = (const float*)d_in[6];
    const float* gb2   = (const float*)d_in[7];
    const float* pn_g  = (const float*)d_in[8];
    const float* pn_b  = (const float*)d_in[9];
    const float* mW1   = (const float*)d_in[10];
    const float* mb1   = (const float*)d_in[11];
    const float* mln_g = (const float*)d_in[12];
    const float* mln_b = (const float*)d_in[13];
    const float* mW2   = (const float*)d_in[14];
    const float* mb2   = (const float*)d_in[15];
    float* logits = (float*)d_out;

    char* ws = (char*)d_ws;
    u16*   Wf     = (u16*)  (ws);                       // 1 MB
    float* gate   = (float*)(ws + (1 << 20));           // 400 KB
    float* pooled = (float*)(ws + (1 << 20) + 409600);  // 512 KB

    hipLaunchKernelGGL(k_wconv, dim3(256), dim3(256), 0, stream, gW1, Wf);
    hipLaunchKernelGGL(k_gate, dim3(GATE_BLOCKS), dim3(512), 0, stream,
                       x, Wf, gb1, gln_g, gln_b, gW2, gb2, gate);
    hipLaunchKernelGGL(k_pool, dim3(NSEG), dim3(128), 0, stream,
                       ids, gate, x, pooled);
    hipLaunchKernelGGL(k_head, dim3(NSEG), dim3(256), 0, stream,
                       pooled, pn_g, pn_b, mW1, mb1, mln_g, mln_b, mW2, mb2, logits);
}

// Round 3
// 344.833 us; speedup vs baseline: 2.0585x; 2.0585x over previous
//
#include <hip/hip_runtime.h>
#include <stdint.h>

typedef unsigned int u32;
typedef unsigned short u16;

#define NROWS 100000
#define DIM 512
#define HDIM 1024
#define OUTF 250
#define NSEG 256
#define LNEPS 1e-5f
#define BM 64
#define NG 1563            // ceil(NROWS/64)

typedef __bf16 bf16_t;
typedef bf16_t bf16x8 __attribute__((ext_vector_type(8)));
typedef float f32x4 __attribute__((ext_vector_type(4)));

__device__ inline u16 f2bf(float f) {
    u32 u = __float_as_uint(f);
    u = (u + 0x7FFFu + ((u >> 16) & 1u)) >> 16;
    return (u16)u;
}
__device__ inline u32 pack2(float a, float b) {
    return (u32)f2bf(a) | ((u32)f2bf(b) << 16);
}

__device__ inline int lower_bound(const int* __restrict__ a, int n, int v) {
    int lo = 0, hi = n;
    while (lo < hi) {
        int m = (lo + hi) >> 1;
        if (a[m] < v) lo = m + 1; else hi = m;
    }
    return lo;
}

// ---------------------------------------------------------------------------
// Kernel 0: convert gW1 [1024][512] fp32 -> bf16 fragments in MFMA-linear order
// Wf layout: [ks(16)][nt(64)][lane(64)] x 16B ; element (lane,j):
//   n = nt*16 + (lane&15), k = ks*32 + (lane>>4)*8 + j
// ---------------------------------------------------------------------------
__global__ __launch_bounds__(256) void k_wconv(const float* __restrict__ gW1,
                                               u16* __restrict__ Wf) {
    int gid  = blockIdx.x * 256 + threadIdx.x;   // 0..65535
    int lane = gid & 63;
    int grp  = gid >> 6;                         // ks*64 + nt
    int ks   = grp >> 6, nt = grp & 63;
    int n    = nt * 16 + (lane & 15);
    int k0   = ks * 32 + ((lane >> 4) << 3);
    const float* src = gW1 + (size_t)n * DIM + k0;
    float4 f0 = *reinterpret_cast<const float4*>(src);
    float4 f1 = *reinterpret_cast<const float4*>(src + 4);
    uint4 val;
    val.x = pack2(f0.x, f0.y); val.y = pack2(f0.z, f0.w);
    val.z = pack2(f1.x, f1.y); val.w = pack2(f1.z, f1.w);
    reinterpret_cast<uint4*>(Wf)[gid] = val;
}

// ---------------------------------------------------------------------------
// Kernel 1: fused  gate[i] = relu(LN(x_i @ gW1.T + gb1)) . gW2 + gb2
// BM=64 rows/block (grid 1563), 8 waves, wave w owns cols [128w,128w+128).
// Simple load->sync->compute structure (round-1 skeleton; no interleave,
// which caused the round-2 spill storm). acc[4][8] = 128 AGPRs.
// ---------------------------------------------------------------------------
__global__ __launch_bounds__(512) void k_gate(
    const float* __restrict__ x, const u16* __restrict__ Wf,
    const float* __restrict__ gb1,
    const float* __restrict__ gln_g, const float* __restrict__ gln_b,
    const float* __restrict__ gW2, const float* __restrict__ gb2,
    float* __restrict__ gate)
{
    __shared__ __align__(16) u16 xlds[BM * DIM];   // 64KB, XOR-swizzled 16B units
    __shared__ float redS[8][BM];
    __shared__ float redQ[8][BM];
    __shared__ float meanA[BM], rstdA[BM];

    const int tid  = threadIdx.x;
    const int lane = tid & 63;
    const int w    = tid >> 6;          // wave 0..7
    const int l15  = lane & 15;
    const int g4   = lane >> 4;         // 0..3
    const int row0 = blockIdx.x * BM;

    // ---- stage x rows -> LDS bf16 (swizzled: unit u of row r at (u ^ (r&7)))
    #pragma unroll
    for (int uu = 0; uu < 8; ++uu) {
        int lu  = uu * 512 + tid;       // unit id 0..4095 (unit = 8 elements)
        int r   = lu >> 6;
        int u   = lu & 63;
        int row = row0 + r;
        row = (row < NROWS) ? row : (NROWS - 1);
        const float* src = x + (size_t)row * DIM + (u << 3);
        float4 f0 = *reinterpret_cast<const float4*>(src);
        float4 f1 = *reinterpret_cast<const float4*>(src + 4);
        uint4 val;
        val.x = pack2(f0.x, f0.y); val.y = pack2(f0.z, f0.w);
        val.z = pack2(f1.x, f1.y); val.w = pack2(f1.z, f1.w);
        int phys = r * DIM + ((u ^ (r & 7)) << 3);   // u16 units
        *reinterpret_cast<uint4*>(&xlds[phys]) = val;
    }
    __syncthreads();

    // ---- K loop: acc[m][t] rows 16m+g4*4+j , col 16*(8w+t)+l15
    f32x4 acc[4][8];
    #pragma unroll
    for (int m = 0; m < 4; ++m)
        #pragma unroll
        for (int t = 0; t < 8; ++t)
            acc[m][t] = (f32x4){0.f, 0.f, 0.f, 0.f};

    const bf16x8* __restrict__ WfB = reinterpret_cast<const bf16x8*>(Wf);

    #pragma unroll 4
    for (int ks = 0; ks < 16; ++ks) {
        bf16x8 b[8];
        #pragma unroll
        for (int t = 0; t < 8; ++t)
            b[t] = WfB[(ks * 64 + w * 8 + t) * 64 + lane];
        bf16x8 a[4];
        #pragma unroll
        for (int m = 0; m < 4; ++m) {
            int r    = m * 16 + l15;
            int u    = ks * 4 + g4;
            int phys = r * DIM + ((u ^ (r & 7)) << 3);
            a[m] = *reinterpret_cast<const bf16x8*>(&xlds[phys]);
        }
        #pragma unroll
        for (int m = 0; m < 4; ++m)
            #pragma unroll
            for (int t = 0; t < 8; ++t)
                acc[m][t] = __builtin_amdgcn_mfma_f32_16x16x32_bf16(a[m], b[t], acc[m][t], 0, 0, 0);
    }

    // ---- bias add (affects LN stats)
    float cbias[8];
    #pragma unroll
    for (int t = 0; t < 8; ++t) cbias[t] = gb1[(w * 8 + t) * 16 + l15];
    #pragma unroll
    for (int m = 0; m < 4; ++m)
        #pragma unroll
        for (int t = 0; t < 8; ++t)
            #pragma unroll
            for (int j = 0; j < 4; ++j)
                acc[m][t][j] += cbias[t];

    // ---- per-row LN stats, streamed per row-slot (low reg pressure)
    #pragma unroll
    for (int m = 0; m < 4; ++m) {
        #pragma unroll
        for (int j = 0; j < 4; ++j) {
            float s1 = 0.f, s2 = 0.f;
            #pragma unroll
            for (int t = 0; t < 8; ++t) {
                float v = acc[m][t][j];
                s1 += v; s2 += v * v;
            }
            #pragma unroll
            for (int off = 1; off < 16; off <<= 1) {
                s1 += __shfl_xor(s1, off);
                s2 += __shfl_xor(s2, off);
            }
            if (l15 == 0) {
                int row = m * 16 + g4 * 4 + j;
                redS[w][row] = s1;
                redQ[w][row] = s2;
            }
        }
    }
    __syncthreads();
    if (tid < BM) {
        float S1 = 0.f, S2 = 0.f;
        #pragma unroll
        for (int ww = 0; ww < 8; ++ww) { S1 += redS[ww][tid]; S2 += redQ[ww][tid]; }
        float mean = S1 * (1.0f / 1024.0f);
        float var  = S2 * (1.0f / 1024.0f) - mean * mean;
        meanA[tid] = mean;
        rstdA[tid] = rsqrtf(var + LNEPS);
    }
    __syncthreads();

    // ---- LN + relu + dot(gW2), streamed per row-slot
    float cg[8], cb[8], cw[8];
    #pragma unroll
    for (int t = 0; t < 8; ++t) {
        int c = (w * 8 + t) * 16 + l15;
        cg[t] = gln_g[c]; cb[t] = gln_b[c]; cw[t] = gW2[c];
    }
    #pragma unroll
    for (int m = 0; m < 4; ++m) {
        #pragma unroll
        for (int j = 0; j < 4; ++j) {
            int row = m * 16 + g4 * 4 + j;
            float mn = meanA[row];
            float rs = rstdA[row];
            float gp = 0.f;
            #pragma unroll
            for (int t = 0; t < 8; ++t) {
                float h = (acc[m][t][j] - mn) * rs * cg[t] + cb[t];
                gp += fmaxf(h, 0.f) * cw[t];
            }
            #pragma unroll
            for (int off = 1; off < 16; off <<= 1)
                gp += __shfl_xor(gp, off);
            if (l15 == 0) redS[w][row] = gp;
        }
    }
    __syncthreads();
    if (tid < BM) {
        float s = gb2[0];
        #pragma unroll
        for (int ww = 0; ww < 8; ++ww) s += redS[ww][tid];
        int row = row0 + tid;
        if (row < NROWS) gate[row] = s;
    }
}

// ---------------------------------------------------------------------------
// Kernel 2: per-segment max and sum(exp)
// ---------------------------------------------------------------------------
__global__ __launch_bounds__(256) void k_seg(const int* __restrict__ ids,
                                             const float* __restrict__ gate,
                                             float* __restrict__ segmax,
                                             float* __restrict__ segden) {
    int b = blockIdx.x, tid = threadIdx.x;
    int start = lower_bound(ids, NROWS, b);
    int end   = lower_bound(ids, NROWS, b + 1);
    __shared__ float sh[4];

    float lm = -INFINITY;
    for (int i = start + tid; i < end; i += 256) lm = fmaxf(lm, gate[i]);
    #pragma unroll
    for (int off = 32; off; off >>= 1) lm = fmaxf(lm, __shfl_xor(lm, off));
    if ((tid & 63) == 0) sh[tid >> 6] = lm;
    __syncthreads();
    float m = fmaxf(fmaxf(sh[0], sh[1]), fmaxf(sh[2], sh[3]));
    __syncthreads();

    float ls = 0.f;
    for (int i = start + tid; i < end; i += 256) ls += __expf(gate[i] - m);
    #pragma unroll
    for (int off = 32; off; off >>= 1) ls += __shfl_xor(ls, off);
    if ((tid & 63) == 0) sh[tid >> 6] = ls;
    __syncthreads();
    if (tid == 0) {
        segmax[b] = m;
        segden[b] = sh[0] + sh[1] + sh[2] + sh[3];
    }
}

// ---------------------------------------------------------------------------
// Kernel 3: pooled[b][:] = sum_i w_i * x[i][:]
// One block per segment, 512 threads = 4 row-stripes x 128 f4-column-slots.
// ---------------------------------------------------------------------------
__global__ __launch_bounds__(512) void k_pool(const int* __restrict__ ids,
                                              const float* __restrict__ gate,
                                              const float* __restrict__ x,
                                              const float* __restrict__ segmax,
                                              const float* __restrict__ segden,
                                              float* __restrict__ pooled) {
    const int b = blockIdx.x, tid = threadIdx.x;
    const int slot   = tid & 127;     // f4 column slot (512 cols / 4)
    const int stripe = tid >> 7;      // 0..3
    const int start = lower_bound(ids, NROWS, b);
    const int end   = lower_bound(ids, NROWS, b + 1);
    const float m   = segmax[b];
    const float den = segden[b];
    const float inv = (den > 0.f) ? 1.0f / den : 0.0f;

    __shared__ f32x4 sh[4][128];   // 8 KB

    const f32x4* __restrict__ xr = reinterpret_cast<const f32x4*>(x);
    f32x4 acc = (f32x4){0.f, 0.f, 0.f, 0.f};
    for (int i = start + stripe; i < end; i += 4) {
        float wgt = __expf(gate[i] - m) * inv;
        f32x4 xv = xr[(size_t)i * 128 + slot];
        acc += wgt * xv;
    }
    sh[stripe][slot] = acc;
    __syncthreads();
    if (tid < 128) {
        f32x4 r = sh[0][tid] + sh[1][tid] + sh[2][tid] + sh[3][tid];
        reinterpret_cast<f32x4*>(pooled)[b * 128 + tid] = r;
    }
}

// ---------------------------------------------------------------------------
// Kernel 4: fused head: out=LN(pooled); z=relu(LN(out@mW1.T+mb1)); logits=z@mW2.T+mb2
// ---------------------------------------------------------------------------
__device__ inline float block_sum(float v, float* sh, int tid) {
    #pragma unroll
    for (int off = 32; off; off >>= 1) v += __shfl_xor(v, off);
    if ((tid & 63) == 0) sh[tid >> 6] = v;
    __syncthreads();
    float r = sh[0] + sh[1] + sh[2] + sh[3];
    __syncthreads();
    return r;
}

__global__ __launch_bounds__(256) void k_head(
    const float* __restrict__ pooled,
    const float* __restrict__ pn_g, const float* __restrict__ pn_b,
    const float* __restrict__ mW1, const float* __restrict__ mb1,
    const float* __restrict__ mln_g, const float* __restrict__ mln_b,
    const float* __restrict__ mW2, const float* __restrict__ mb2,
    float* __restrict__ logits)
{
    const int b = blockIdx.x, tid = threadIdx.x;
    __shared__ float outr[DIM];
    __shared__ float zr[HDIM];
    __shared__ float shred[4];

    float v0 = pooled[b * DIM + tid];
    float v1 = pooled[b * DIM + 256 + tid];
    float S = block_sum(v0 + v1, shred, tid);
    float Q = block_sum(v0 * v0 + v1 * v1, shred, tid);
    float mean = S * (1.0f / 512.0f);
    float rstd = rsqrtf(Q * (1.0f / 512.0f) - mean * mean + LNEPS);
    outr[tid]       = (v0 - mean) * rstd * pn_g[tid] + pn_b[tid];
    outr[tid + 256] = (v1 - mean) * rstd * pn_g[tid + 256] + pn_b[tid + 256];
    __syncthreads();

    float y[4];
    #pragma unroll
    for (int q = 0; q < 4; ++q) {
        int f = q * 256 + tid;
        const float4* wr = reinterpret_cast<const float4*>(mW1 + (size_t)f * DIM);
        float acc = 0.f;
        #pragma unroll 8
        for (int kk = 0; kk < 128; ++kk) {
            float4 wv = wr[kk];
            acc += wv.x * outr[kk * 4 + 0] + wv.y * outr[kk * 4 + 1]
                 + wv.z * outr[kk * 4 + 2] + wv.w * outr[kk * 4 + 3];
        }
        y[q] = acc + mb1[f];
    }
    float S2 = block_sum(y[0] + y[1] + y[2] + y[3], shred, tid);
    float Q2 = block_sum(y[0]*y[0] + y[1]*y[1] + y[2]*y[2] + y[3]*y[3], shred, tid);
    float mean2 = S2 * (1.0f / 1024.0f);
    float rstd2 = rsqrtf(Q2 * (1.0f / 1024.0f) - mean2 * mean2 + LNEPS);
    #pragma unroll
    for (int q = 0; q < 4; ++q) {
        int f = q * 256 + tid;
        zr[f] = fmaxf((y[q] - mean2) * rstd2 * mln_g[f] + mln_b[f], 0.f);
    }
    __syncthreads();
    if (tid < OUTF) {
        const float4* wr = reinterpret_cast<const float4*>(mW2 + (size_t)tid * HDIM);
        float acc = 0.f;
        #pragma unroll 8
        for (int kk = 0; kk < 256; ++kk) {
            float4 wv = wr[kk];
            acc += wv.x * zr[kk * 4 + 0] + wv.y * zr[kk * 4 + 1]
                 + wv.z * zr[kk * 4 + 2] + wv.w * zr[kk * 4 + 3];
        }
        logits[b * OUTF + tid] = acc + mb2[tid];
    }
}

// ---------------------------------------------------------------------------
extern "C" void kernel_launch(void* const* d_in, const int* in_sizes, int n_in,
                              void* d_out, int out_size, void* d_ws, size_t ws_size,
                              hipStream_t stream) {
    const float* x     = (const float*)d_in[0];
    const int*   ids   = (const int*)  d_in[1];
    const float* gW1   = (const float*)d_in[2];
    const float* gb1   = (const float*)d_in[3];
    const float* gln_g = (const float*)d_in[4];
    const float* gln_b = (const float*)d_in[5];
    const float* gW2   = (const float*)d_in[6];
    const float* gb2   = (const float*)d_in[7];
    const float* pn_g  = (const float*)d_in[8];
    const float* pn_b  = (const float*)d_in[9];
    const float* mW1   = (const float*)d_in[10];
    const float* mb1   = (const float*)d_in[11];
    const float* mln_g = (const float*)d_in[12];
    const float* mln_b = (const float*)d_in[13];
    const float* mW2   = (const float*)d_in[14];
    const float* mb2   = (const float*)d_in[15];
    float* logits = (float*)d_out;

    char* ws = (char*)d_ws;
    u16*   Wf     = (u16*)  (ws);                       // 1 MB
    float* gate   = (float*)(ws + (1 << 20));           // 400 KB
    float* segmax = (float*)(ws + (1 << 20) + 409600);  // 1 KB
    float* segden = segmax + 256;
    float* pooled = (float*)(ws + (1 << 20) + 409600 + 4096);  // 512 KB

    hipLaunchKernelGGL(k_wconv, dim3(256), dim3(256), 0, stream, gW1, Wf);
    hipLaunchKernelGGL(k_gate, dim3(NG), dim3(512), 0, stream,
                       x, Wf, gb1, gln_g, gln_b, gW2, gb2, gate);
    hipLaunchKernelGGL(k_seg, dim3(NSEG), dim3(256), 0, stream, ids, gate, segmax, segden);
    hipLaunchKernelGGL(k_pool, dim3(NSEG), dim3(512), 0, stream,
                       ids, gate, x, segmax, segden, pooled);
    hipLaunchKernelGGL(k_head, dim3(NSEG), dim3(256), 0, stream,
                       pooled, pn_g, pn_b, mW1, mb1, mln_g, mln_b, mW2, mb2, logits);
}

// Round 4
// 302.441 us; speedup vs baseline: 2.3470x; 1.1402x over previous
//
#include <hip/hip_runtime.h>
#include <stdint.h>

typedef unsigned int u32;
typedef unsigned short u16;

#define NROWS 100000
#define DIM 512
#define HDIM 1024
#define OUTF 250
#define NSEG 256
#define LNEPS 1e-5f
#define BM 32
#define NG 3125            // 100000/32

typedef __bf16 bf16_t;
typedef bf16_t bf16x8 __attribute__((ext_vector_type(8)));
typedef float f32x4 __attribute__((ext_vector_type(4)));

__device__ inline u16 f2bf(float f) {
    u32 u = __float_as_uint(f);
    u = (u + 0x7FFFu + ((u >> 16) & 1u)) >> 16;
    return (u16)u;
}
__device__ inline u32 pack2(float a, float b) {
    return (u32)f2bf(a) | ((u32)f2bf(b) << 16);
}

__device__ inline int lower_bound(const int* __restrict__ a, int n, int v) {
    int lo = 0, hi = n;
    while (lo < hi) {
        int m = (lo + hi) >> 1;
        if (a[m] < v) lo = m + 1; else hi = m;
    }
    return lo;
}

// ---------------------------------------------------------------------------
// Kernel 0: convert gW1 [1024][512] fp32 -> bf16 fragments in MFMA-linear order
// Wf layout: [ks(16)][nt(64)][lane(64)] x 16B ; element (lane,j):
//   n = nt*16 + (lane&15), k = ks*32 + (lane>>4)*8 + j
// ---------------------------------------------------------------------------
__global__ __launch_bounds__(256) void k_wconv(const float* __restrict__ gW1,
                                               u16* __restrict__ Wf) {
    int gid  = blockIdx.x * 256 + threadIdx.x;   // 0..65535
    int lane = gid & 63;
    int grp  = gid >> 6;                         // ks*64 + nt
    int ks   = grp >> 6, nt = grp & 63;
    int n    = nt * 16 + (lane & 15);
    int k0   = ks * 32 + ((lane >> 4) << 3);
    const float* src = gW1 + (size_t)n * DIM + k0;
    float4 f0 = *reinterpret_cast<const float4*>(src);
    float4 f1 = *reinterpret_cast<const float4*>(src + 4);
    uint4 val;
    val.x = pack2(f0.x, f0.y); val.y = pack2(f0.z, f0.w);
    val.z = pack2(f1.x, f1.y); val.w = pack2(f1.z, f1.w);
    reinterpret_cast<uint4*>(Wf)[gid] = val;
}

// ---------------------------------------------------------------------------
// Kernel 1: fused  gate[i] = relu(LN(x_i @ gW1.T + gb1)) . gW2 + gb2
// BM=32 rows/block (grid 3125), 8 waves, wave w owns cols [128w,128w+128).
// K-loop software-pipelined: B-frags (L2) and A-frags (LDS) double-buffered
// in registers, loaded one ks ahead of use (even/odd fully-unrolled).
// ---------------------------------------------------------------------------
__global__ __launch_bounds__(512) void k_gate(
    const float* __restrict__ x, const u16* __restrict__ Wf,
    const float* __restrict__ gb1,
    const float* __restrict__ gln_g, const float* __restrict__ gln_b,
    const float* __restrict__ gW2, const float* __restrict__ gb2,
    float* __restrict__ gate)
{
    __shared__ __align__(16) u16 xlds[BM * DIM];   // 32KB, XOR-swizzled 16B units
    __shared__ float redS[8][BM];
    __shared__ float redQ[8][BM];
    __shared__ float meanA[BM], rstdA[BM];

    const int tid  = threadIdx.x;
    const int lane = tid & 63;
    const int w    = tid >> 6;          // wave 0..7
    const int l15  = lane & 15;
    const int g4   = lane >> 4;         // 0..3
    const int row0 = blockIdx.x * BM;

    // ---- stage x rows -> LDS bf16 (swizzled: unit u of row r at (u ^ (r&7)))
    #pragma unroll
    for (int uu = 0; uu < 4; ++uu) {
        int lu  = uu * 512 + tid;       // unit id 0..2047 (unit = 8 elements)
        int r   = lu >> 6;
        int u   = lu & 63;
        const float* src = x + (size_t)(row0 + r) * DIM + (u << 3);
        float4 f0 = *reinterpret_cast<const float4*>(src);
        float4 f1 = *reinterpret_cast<const float4*>(src + 4);
        bf16x8 v;
        v[0] = (bf16_t)f0.x; v[1] = (bf16_t)f0.y;
        v[2] = (bf16_t)f0.z; v[3] = (bf16_t)f0.w;
        v[4] = (bf16_t)f1.x; v[5] = (bf16_t)f1.y;
        v[6] = (bf16_t)f1.z; v[7] = (bf16_t)f1.w;
        int phys = r * DIM + ((u ^ (r & 7)) << 3);   // u16 units
        *reinterpret_cast<bf16x8*>(&xlds[phys]) = v;
    }
    __syncthreads();

    // ---- pipelined K loop
    f32x4 acc[2][8];
    #pragma unroll
    for (int m = 0; m < 2; ++m)
        #pragma unroll
        for (int t = 0; t < 8; ++t)
            acc[m][t] = (f32x4){0.f, 0.f, 0.f, 0.f};

    const bf16x8* __restrict__ WfB = reinterpret_cast<const bf16x8*>(Wf);

    auto loadB = [&](bf16x8 (&b)[8], int ks) {
        #pragma unroll
        for (int t = 0; t < 8; ++t)
            b[t] = WfB[(ks * 64 + w * 8 + t) * 64 + lane];
    };
    auto loadA = [&](bf16x8 (&a)[2], int ks) {
        #pragma unroll
        for (int m = 0; m < 2; ++m) {
            int r = m * 16 + l15;
            int u = ks * 4 + g4;
            a[m] = *reinterpret_cast<const bf16x8*>(&xlds[r * DIM + ((u ^ (r & 7)) << 3)]);
        }
    };
    auto domfma = [&](bf16x8 (&a)[2], bf16x8 (&b)[8]) {
        #pragma unroll
        for (int m = 0; m < 2; ++m)
            #pragma unroll
            for (int t = 0; t < 8; ++t)
                acc[m][t] = __builtin_amdgcn_mfma_f32_16x16x32_bf16(a[m], b[t], acc[m][t], 0, 0, 0);
    };

    bf16x8 b0[8], b1[8], a0[2], a1[2];
    loadB(b0, 0); loadA(a0, 0);
    #pragma unroll
    for (int ks2 = 0; ks2 < 8; ++ks2) {
        loadB(b1, 2 * ks2 + 1);
        loadA(a1, 2 * ks2 + 1);
        domfma(a0, b0);
        if (ks2 < 7) {
            loadB(b0, 2 * ks2 + 2);
            loadA(a0, 2 * ks2 + 2);
        }
        domfma(a1, b1);
    }

    // ---- bias add (affects LN stats)
    float cbias[8];
    #pragma unroll
    for (int t = 0; t < 8; ++t) cbias[t] = gb1[(w * 8 + t) * 16 + l15];
    #pragma unroll
    for (int m = 0; m < 2; ++m)
        #pragma unroll
        for (int t = 0; t < 8; ++t)
            #pragma unroll
            for (int j = 0; j < 4; ++j)
                acc[m][t][j] += cbias[t];

    // ---- per-row LN stats, streamed per row-slot
    #pragma unroll
    for (int m = 0; m < 2; ++m) {
        #pragma unroll
        for (int j = 0; j < 4; ++j) {
            float s1 = 0.f, s2 = 0.f;
            #pragma unroll
            for (int t = 0; t < 8; ++t) {
                float v = acc[m][t][j];
                s1 += v; s2 += v * v;
            }
            #pragma unroll
            for (int off = 1; off < 16; off <<= 1) {
                s1 += __shfl_xor(s1, off);
                s2 += __shfl_xor(s2, off);
            }
            if (l15 == 0) {
                int row = m * 16 + g4 * 4 + j;
                redS[w][row] = s1;
                redQ[w][row] = s2;
            }
        }
    }
    __syncthreads();
    if (tid < BM) {
        float S1 = 0.f, S2 = 0.f;
        #pragma unroll
        for (int ww = 0; ww < 8; ++ww) { S1 += redS[ww][tid]; S2 += redQ[ww][tid]; }
        float mean = S1 * (1.0f / 1024.0f);
        float var  = S2 * (1.0f / 1024.0f) - mean * mean;
        meanA[tid] = mean;
        rstdA[tid] = rsqrtf(var + LNEPS);
    }
    __syncthreads();

    // ---- LN + relu + dot(gW2), streamed per row-slot
    float cg[8], cb[8], cw[8];
    #pragma unroll
    for (int t = 0; t < 8; ++t) {
        int c = (w * 8 + t) * 16 + l15;
        cg[t] = gln_g[c]; cb[t] = gln_b[c]; cw[t] = gW2[c];
    }
    #pragma unroll
    for (int m = 0; m < 2; ++m) {
        #pragma unroll
        for (int j = 0; j < 4; ++j) {
            int row = m * 16 + g4 * 4 + j;
            float mn = meanA[row];
            float rs = rstdA[row];
            float gp = 0.f;
            #pragma unroll
            for (int t = 0; t < 8; ++t) {
                float h = (acc[m][t][j] - mn) * rs * cg[t] + cb[t];
                gp += fmaxf(h, 0.f) * cw[t];
            }
            #pragma unroll
            for (int off = 1; off < 16; off <<= 1)
                gp += __shfl_xor(gp, off);
            if (l15 == 0) redS[w][row] = gp;
        }
    }
    __syncthreads();
    if (tid < BM) {
        float s = gb2[0];
        #pragma unroll
        for (int ww = 0; ww < 8; ++ww) s += redS[ww][tid];
        gate[row0 + tid] = s;
    }
}

// ---------------------------------------------------------------------------
// Kernel 2: per-segment max and sum(exp)
// ---------------------------------------------------------------------------
__global__ __launch_bounds__(256) void k_seg(const int* __restrict__ ids,
                                             const float* __restrict__ gate,
                                             float* __restrict__ segmax,
                                             float* __restrict__ segden) {
    int b = blockIdx.x, tid = threadIdx.x;
    int start = lower_bound(ids, NROWS, b);
    int end   = lower_bound(ids, NROWS, b + 1);
    __shared__ float sh[4];

    float lm = -INFINITY;
    for (int i = start + tid; i < end; i += 256) lm = fmaxf(lm, gate[i]);
    #pragma unroll
    for (int off = 32; off; off >>= 1) lm = fmaxf(lm, __shfl_xor(lm, off));
    if ((tid & 63) == 0) sh[tid >> 6] = lm;
    __syncthreads();
    float m = fmaxf(fmaxf(sh[0], sh[1]), fmaxf(sh[2], sh[3]));
    __syncthreads();

    float ls = 0.f;
    for (int i = start + tid; i < end; i += 256) ls += __expf(gate[i] - m);
    #pragma unroll
    for (int off = 32; off; off >>= 1) ls += __shfl_xor(ls, off);
    if ((tid & 63) == 0) sh[tid >> 6] = ls;
    __syncthreads();
    if (tid == 0) {
        segmax[b] = m;
        segden[b] = sh[0] + sh[1] + sh[2] + sh[3];
    }
}

// ---------------------------------------------------------------------------
// Kernel 3: pooled[b][:] = sum_i w_i * x[i][:]
// One block per segment, 512 threads = 4 row-stripes x 128 f4-column-slots.
// ---------------------------------------------------------------------------
__global__ __launch_bounds__(512) void k_pool(const int* __restrict__ ids,
                                              const float* __restrict__ gate,
                                              const float* __restrict__ x,
                                              const float* __restrict__ segmax,
                                              const float* __restrict__ segden,
                                              float* __restrict__ pooled) {
    const int b = blockIdx.x, tid = threadIdx.x;
    const int slot   = tid & 127;     // f4 column slot (512 cols / 4)
    const int stripe = tid >> 7;      // 0..3
    const int start = lower_bound(ids, NROWS, b);
    const int end   = lower_bound(ids, NROWS, b + 1);
    const float m   = segmax[b];
    const float den = segden[b];
    const float inv = (den > 0.f) ? 1.0f / den : 0.0f;

    __shared__ f32x4 sh[4][128];   // 8 KB

    const f32x4* __restrict__ xr = reinterpret_cast<const f32x4*>(x);
    f32x4 acc = (f32x4){0.f, 0.f, 0.f, 0.f};
    for (int i = start + stripe; i < end; i += 4) {
        float wgt = __expf(gate[i] - m) * inv;
        f32x4 xv = xr[(size_t)i * 128 + slot];
        acc += wgt * xv;
    }
    sh[stripe][slot] = acc;
    __syncthreads();
    if (tid < 128) {
        f32x4 r = sh[0][tid] + sh[1][tid] + sh[2][tid] + sh[3][tid];
        reinterpret_cast<f32x4*>(pooled)[b * 128 + tid] = r;
    }
}

// ---------------------------------------------------------------------------
// Kernel 4: fused head: out=LN(pooled); z=relu(LN(out@mW1.T+mb1)); logits=z@mW2.T+mb2
// ---------------------------------------------------------------------------
__device__ inline float block_sum(float v, float* sh, int tid) {
    #pragma unroll
    for (int off = 32; off; off >>= 1) v += __shfl_xor(v, off);
    if ((tid & 63) == 0) sh[tid >> 6] = v;
    __syncthreads();
    float r = sh[0] + sh[1] + sh[2] + sh[3];
    __syncthreads();
    return r;
}

__global__ __launch_bounds__(256) void k_head(
    const float* __restrict__ pooled,
    const float* __restrict__ pn_g, const float* __restrict__ pn_b,
    const float* __restrict__ mW1, const float* __restrict__ mb1,
    const float* __restrict__ mln_g, const float* __restrict__ mln_b,
    const float* __restrict__ mW2, const float* __restrict__ mb2,
    float* __restrict__ logits)
{
    const int b = blockIdx.x, tid = threadIdx.x;
    __shared__ float outr[DIM];
    __shared__ float zr[HDIM];
    __shared__ float shred[4];

    float v0 = pooled[b * DIM + tid];
    float v1 = pooled[b * DIM + 256 + tid];
    float S = block_sum(v0 + v1, shred, tid);
    float Q = block_sum(v0 * v0 + v1 * v1, shred, tid);
    float mean = S * (1.0f / 512.0f);
    float rstd = rsqrtf(Q * (1.0f / 512.0f) - mean * mean + LNEPS);
    outr[tid]       = (v0 - mean) * rstd * pn_g[tid] + pn_b[tid];
    outr[tid + 256] = (v1 - mean) * rstd * pn_g[tid + 256] + pn_b[tid + 256];
    __syncthreads();

    float y[4];
    #pragma unroll
    for (int q = 0; q < 4; ++q) {
        int f = q * 256 + tid;
        const float4* wr = reinterpret_cast<const float4*>(mW1 + (size_t)f * DIM);
        float acc = 0.f;
        #pragma unroll 8
        for (int kk = 0; kk < 128; ++kk) {
            float4 wv = wr[kk];
            acc += wv.x * outr[kk * 4 + 0] + wv.y * outr[kk * 4 + 1]
                 + wv.z * outr[kk * 4 + 2] + wv.w * outr[kk * 4 + 3];
        }
        y[q] = acc + mb1[f];
    }
    float S2 = block_sum(y[0] + y[1] + y[2] + y[3], shred, tid);
    float Q2 = block_sum(y[0]*y[0] + y[1]*y[1] + y[2]*y[2] + y[3]*y[3], shred, tid);
    float mean2 = S2 * (1.0f / 1024.0f);
    float rstd2 = rsqrtf(Q2 * (1.0f / 1024.0f) - mean2 * mean2 + LNEPS);
    #pragma unroll
    for (int q = 0; q < 4; ++q) {
        int f = q * 256 + tid;
        zr[f] = fmaxf((y[q] - mean2) * rstd2 * mln_g[f] + mln_b[f], 0.f);
    }
    __syncthreads();
    if (tid < OUTF) {
        const float4* wr = reinterpret_cast<const float4*>(mW2 + (size_t)tid * HDIM);
        float acc = 0.f;
        #pragma unroll 8
        for (int kk = 0; kk < 256; ++kk) {
            float4 wv = wr[kk];
            acc += wv.x * zr[kk * 4 + 0] + wv.y * zr[kk * 4 + 1]
                 + wv.z * zr[kk * 4 + 2] + wv.w * zr[kk * 4 + 3];
        }
        logits[b * OUTF + tid] = acc + mb2[tid];
    }
}

// ---------------------------------------------------------------------------
extern "C" void kernel_launch(void* const* d_in, const int* in_sizes, int n_in,
                              void* d_out, int out_size, void* d_ws, size_t ws_size,
                              hipStream_t stream) {
    const float* x     = (const float*)d_in[0];
    const int*   ids   = (const int*)  d_in[1];
    const float* gW1   = (const float*)d_in[2];
    const float* gb1   = (const float*)d_in[3];
    const float* gln_g = (const float*)d_in[4];
    const float* gln_b = (const float*)d_in[5];
    const float* gW2   = (const float*)d_in[6];
    const float* gb2   = (const float*)d_in[7];
    const float* pn_g  = (const float*)d_in[8];
    const float* pn_b  = (const float*)d_in[9];
    const float* mW1   = (const float*)d_in[10];
    const float* mb1   = (const float*)d_in[11];
    const float* mln_g = (const float*)d_in[12];
    const float* mln_b = (const float*)d_in[13];
    const float* mW2   = (const float*)d_in[14];
    const float* mb2   = (const float*)d_in[15];
    float* logits = (float*)d_out;

    char* ws = (char*)d_ws;
    u16*   Wf     = (u16*)  (ws);                       // 1 MB
    float* gate   = (float*)(ws + (1 << 20));           // 400 KB
    float* segmax = (float*)(ws + (1 << 20) + 409600);  // 1 KB
    float* segden = segmax + 256;
    float* pooled = (float*)(ws + (1 << 20) + 409600 + 4096);  // 512 KB

    hipLaunchKernelGGL(k_wconv, dim3(256), dim3(256), 0, stream, gW1, Wf);
    hipLaunchKernelGGL(k_gate, dim3(NG), dim3(512), 0, stream,
                       x, Wf, gb1, gln_g, gln_b, gW2, gb2, gate);
    hipLaunchKernelGGL(k_seg, dim3(NSEG), dim3(256), 0, stream, ids, gate, segmax, segden);
    hipLaunchKernelGGL(k_pool, dim3(NSEG), dim3(512), 0, stream,
                       ids, gate, x, segmax, segden, pooled);
    hipLaunchKernelGGL(k_head, dim3(NSEG), dim3(256), 0, stream,
                       pooled, pn_g, pn_b, mW1, mb1, mln_g, mln_b, mW2, mb2, logits);
}